// Round 1
// baseline (1983.043 us; speedup 1.0000x reference)
//
#include <hip/hip_runtime.h>

#define BB 4
#define CCH 256
#define HH 64
#define WW 64
#define HWSZ 4096
#define NPX 16384
#define NG 32
#define CPG 8
#define EPSV 1e-5f

__device__ __forceinline__ float4 ld4(const float* p) { return *(const float4*)p; }
__device__ __forceinline__ void st4(float* p, float4 v) { *(float4*)p = v; }

// wT[k][co][ci] = w_def[co][ci][k]   (k = kh*3+kw)
__global__ __launch_bounds__(256) void prep_wdef(const float* __restrict__ w1, const float* __restrict__ w2,
                                                 float* __restrict__ o1, float* __restrict__ o2) {
    int idx = blockIdx.x * 256 + threadIdx.x;          // 0 .. 2*589824
    int sel = idx >= 589824;
    int i = sel ? idx - 589824 : idx;
    const float* w = sel ? w2 : w1;
    float* o = sel ? o2 : o1;
    int ci = i & 255, co = (i >> 8) & 255, k = i >> 16;
    o[i] = w[(((co << 8) + ci) * 9) + k];
}

// wOffT[co][k][ci] = w_off[co][ci][k]
__global__ __launch_bounds__(256) void prep_woff(const float* __restrict__ w1, const float* __restrict__ w2,
                                                 float* __restrict__ o1, float* __restrict__ o2) {
    int idx = blockIdx.x * 256 + threadIdx.x;          // 0 .. 2*41472
    int sel = idx >= 41472;
    int i = sel ? idx - 41472 : idx;
    const float* w = sel ? w2 : w1;
    float* o = sel ? o2 : o1;
    int ci = i & 255;
    int rest = i >> 8;          // co*9 + k
    int co = rest / 9, k = rest - co * 9;
    o[i] = w[(((co << 8) + ci) * 9) + k];
}

// NCHW -> NHWC tiled transpose
__global__ __launch_bounds__(256) void transpose_to_nhwc(const float* __restrict__ in, float* __restrict__ out) {
    __shared__ float lds[64][65];
    int bid = blockIdx.x;                 // b*256 + y*4 + cb
    int cb = bid & 3, y = (bid >> 2) & 63, b = bid >> 8;
    int c0 = cb << 6;
    int tid = threadIdx.x;
#pragma unroll
    for (int i = 0; i < 4; ++i) {
        int q = tid + (i << 8);
        int c_l = q >> 4, x4 = (q & 15) << 2;
        float4 v = ld4(&in[((b * 256 + c0 + c_l) << 12) + (y << 6) + x4]);
        lds[c_l][x4 + 0] = v.x; lds[c_l][x4 + 1] = v.y; lds[c_l][x4 + 2] = v.z; lds[c_l][x4 + 3] = v.w;
    }
    __syncthreads();
#pragma unroll
    for (int i = 0; i < 4; ++i) {
        int q = tid + (i << 8);
        int x_l = q >> 4, c4 = (q & 15) << 2;
        float4 v;
        v.x = lds[c4 + 0][x_l]; v.y = lds[c4 + 1][x_l]; v.z = lds[c4 + 2][x_l]; v.w = lds[c4 + 3][x_l];
        st4(&out[((b << 12) + (y << 6) + x_l) * 256 + c0 + c4], v);
    }
}

// 3x3 conv, Cout=18, src in NHWC, weights [co][k][ci], out [px][18]
__global__ __launch_bounds__(256) void offset_conv(const float* __restrict__ src, const float* __restrict__ wT,
                                                   const float* __restrict__ bias, float* __restrict__ offb) {
    int g = blockIdx.x * 256 + threadIdx.x;   // 294912 = 16384*18
    int px = g / 18, co = g - px * 18;
    int b = px >> 12, y = (px >> 6) & 63, x = px & 63;
    float acc = bias[co];
#pragma unroll
    for (int kh = 0; kh < 3; ++kh) {
        int yy = y + kh - 1;
        if (yy < 0 || yy > 63) continue;
#pragma unroll
        for (int kw = 0; kw < 3; ++kw) {
            int xx = x + kw - 1;
            if (xx < 0 || xx > 63) continue;
            const float* xp = src + (((b << 6) + yy) * 64 + xx) * 256;
            const float* wp = wT + (co * 9 + kh * 3 + kw) * 256;
#pragma unroll 8
            for (int ciq = 0; ciq < 64; ++ciq) {
                float4 a = ld4(xp + (ciq << 2));
                float4 w = ld4(wp + (ciq << 2));
                acc += a.x * w.x + a.y * w.y + a.z * w.z + a.w * w.w;
            }
        }
    }
    offb[px * 18 + co] = acc;
}

// Deformable conv: xn NHWC, offb [px][18], wT [k][co][ci], out NHWC [px][co]
__global__ __launch_bounds__(256) void deform_conv_k(const float* __restrict__ xn, const float* __restrict__ offb,
                                                     const float* __restrict__ wT, float* __restrict__ outn) {
    __shared__ float val[64][64];     // [px_local][ci_local]
    __shared__ float wbuf[128][68];   // [co_local][ci_local], padded
    __shared__ int   cidx[4][64];
    __shared__ float cwt[4][64];

    int pxTile = blockIdx.x >> 1;
    int coHalf = blockIdx.x & 1;
    int px0 = pxTile << 6;            // 64 consecutive pixels = one row
    int tid = threadIdx.x;
    int wave = tid >> 6, lane = tid & 63;
    int myPx = wave << 4;
    int coBase = coHalf << 7;

    float acc[16][2];
#pragma unroll
    for (int p = 0; p < 16; ++p) { acc[p][0] = 0.f; acc[p][1] = 0.f; }

    for (int k = 0; k < 9; ++k) {
        if (tid < 64) {
            int px = px0 + tid;
            int b = px >> 12, y = (px >> 6) & 63, x = px & 63;
            float dy = offb[px * 18 + 2 * k];
            float dx = offb[px * 18 + 2 * k + 1];
            float py = dy + (float)(y - 1 + k / 3);
            float pxf = dx + (float)(x - 1 + k % 3);
            float y0f = floorf(py), x0f = floorf(pxf);
            float ly = py - y0f, lx = pxf - x0f;
            int y0 = (int)y0f, x0 = (int)x0f;
            int y1 = y0 + 1, x1 = x0 + 1;
            int base = b << 12;
            bool vy0 = (y0 >= 0) && (y0 < 64), vy1 = (y1 >= 0) && (y1 < 64);
            bool vx0 = (x0 >= 0) && (x0 < 64), vx1 = (x1 >= 0) && (x1 < 64);
            cidx[0][tid] = (vy0 && vx0) ? ((base + (y0 << 6) + x0) << 8) : -1;
            cidx[1][tid] = (vy0 && vx1) ? ((base + (y0 << 6) + x1) << 8) : -1;
            cidx[2][tid] = (vy1 && vx0) ? ((base + (y1 << 6) + x0) << 8) : -1;
            cidx[3][tid] = (vy1 && vx1) ? ((base + (y1 << 6) + x1) << 8) : -1;
            cwt[0][tid] = (1.f - ly) * (1.f - lx);
            cwt[1][tid] = (1.f - ly) * lx;
            cwt[2][tid] = ly * (1.f - lx);
            cwt[3][tid] = ly * lx;
        }
        __syncthreads();
        for (int ch = 0; ch < 4; ++ch) {
            int ci0 = ch << 6;
            // stage weights: wbuf[co_l][ci_l] <- wT[k][coBase+co_l][ci0+ci_l]
#pragma unroll
            for (int i = 0; i < 8; ++i) {
                int q = tid + (i << 8);
                int co_l = q >> 4, ci4 = (q & 15) << 2;
                float4 w = ld4(&wT[(((k << 8) + coBase + co_l) << 8) + ci0 + ci4]);
                st4(&wbuf[co_l][ci4], w);
            }
            // gather val[px_l][ci_l]
#pragma unroll
            for (int i = 0; i < 4; ++i) {
                int q = tid + (i << 8);
                int px_l = q >> 4, ci4 = (q & 15) << 2;
                int cb2 = ci0 + ci4;
                float4 a = {0.f, 0.f, 0.f, 0.f};
#pragma unroll
                for (int c = 0; c < 4; ++c) {
                    int id = cidx[c][px_l];
                    float w = cwt[c][px_l];
                    if (id >= 0) {
                        float4 t = ld4(&xn[id + cb2]);
                        a.x += w * t.x; a.y += w * t.y; a.z += w * t.z; a.w += w * t.w;
                    }
                }
                st4(&val[px_l][ci4], a);
            }
            __syncthreads();
            // GEMM phase
#pragma unroll 2
            for (int g2 = 0; g2 < 16; ++g2) {
                float4 w0 = ld4(&wbuf[lane][g2 << 2]);
                float4 w1 = ld4(&wbuf[64 + lane][g2 << 2]);
#pragma unroll
                for (int p = 0; p < 16; ++p) {
                    float4 v = ld4(&val[myPx + p][g2 << 2]);
                    acc[p][0] += v.x * w0.x + v.y * w0.y + v.z * w0.z + v.w * w0.w;
                    acc[p][1] += v.x * w1.x + v.y * w1.y + v.z * w1.z + v.w * w1.w;
                }
            }
            __syncthreads();
        }
    }
#pragma unroll
    for (int p = 0; p < 16; ++p) {
        int row = (px0 + myPx + p) << 8;
        outn[row + coBase + lane] = acc[p][0];
        outn[row + coBase + 64 + lane] = acc[p][1];
    }
}

// GroupNorm stats over NHWC buffer: per (b,g) mean & rstd
__global__ __launch_bounds__(256) void gn_stats(const float* __restrict__ buf, float* __restrict__ stats) {
    int bid = blockIdx.x;     // b*32+g
    int b = bid >> 5, g = bid & 31;
    const float* p = buf + (b << 20) + (g << 3);
    float s = 0.f, s2 = 0.f;
    for (int j = threadIdx.x; j < 32768; j += 256) {
        int px = j >> 3, c = j & 7;
        float v = p[(px << 8) + c];
        s += v; s2 += v * v;
    }
#pragma unroll
    for (int o = 32; o > 0; o >>= 1) { s += __shfl_down(s, o, 64); s2 += __shfl_down(s2, o, 64); }
    __shared__ float ws1[4], ws2[4];
    int wv = threadIdx.x >> 6, lane = threadIdx.x & 63;
    if (lane == 0) { ws1[wv] = s; ws2[wv] = s2; }
    __syncthreads();
    if (threadIdx.x == 0) {
        float t1 = ws1[0] + ws1[1] + ws1[2] + ws1[3];
        float t2 = ws2[0] + ws2[1] + ws2[2] + ws2[3];
        float mean = t1 * (1.f / 32768.f);
        float var = t2 * (1.f / 32768.f) - mean * mean;
        stats[bid * 2] = mean;
        stats[bid * 2 + 1] = rsqrtf(var + EPSV);
    }
}

// in-place GN + ReLU on NHWC buffer
__global__ __launch_bounds__(256) void gn_apply_relu(float* __restrict__ buf, const float* __restrict__ stats,
                                                     const float* __restrict__ gamma, const float* __restrict__ beta) {
    int q = blockIdx.x * 256 + threadIdx.x;   // 1,048,576 float4s
    int e0 = q << 2;
    int c0 = e0 & 255;
    int b = e0 >> 20;
    int g = c0 >> 3;
    float mean = stats[((b << 5) + g) * 2];
    float rstd = stats[((b << 5) + g) * 2 + 1];
    float4 v = ld4(&buf[e0]);
    float4 ga = ld4(&gamma[c0]);
    float4 be = ld4(&beta[c0]);
    v.x = fmaxf((v.x - mean) * rstd * ga.x + be.x, 0.f);
    v.y = fmaxf((v.y - mean) * rstd * ga.y + be.y, 0.f);
    v.z = fmaxf((v.z - mean) * rstd * ga.z + be.z, 0.f);
    v.w = fmaxf((v.w - mean) * rstd * ga.w + be.w, 0.f);
    st4(&buf[e0], v);
}

// NHWC -> NCHW with fused GN2 + residual + ReLU
__global__ __launch_bounds__(256) void final_kernel(const float* __restrict__ v2, const float* __restrict__ stats,
                                                    const float* __restrict__ gamma, const float* __restrict__ beta,
                                                    const float* __restrict__ xin, float* __restrict__ out) {
    __shared__ float lds[64][65];
    int bid = blockIdx.x;
    int cb = bid & 3, y = (bid >> 2) & 63, b = bid >> 8;
    int c0 = cb << 6;
    int tid = threadIdx.x;
#pragma unroll
    for (int i = 0; i < 4; ++i) {
        int q = tid + (i << 8);
        int x_l = q >> 4, c4 = (q & 15) << 2;
        float4 v = ld4(&v2[((b << 12) + (y << 6) + x_l) * 256 + c0 + c4]);
        lds[c4 + 0][x_l] = v.x; lds[c4 + 1][x_l] = v.y; lds[c4 + 2][x_l] = v.z; lds[c4 + 3][x_l] = v.w;
    }
    __syncthreads();
#pragma unroll
    for (int i = 0; i < 4; ++i) {
        int q = tid + (i << 8);
        int c_l = q >> 4, x4 = (q & 15) << 2;
        int c = c0 + c_l;
        int g = c >> 3;
        float mean = stats[((b << 5) + g) * 2];
        float rstd = stats[((b << 5) + g) * 2 + 1];
        float ga = gamma[c], be = beta[c];
        const float* xp = &xin[((b << 8) + c) * 4096 + (y << 6) + x4];
        float4 r = ld4(xp);
        float4 o;
        o.x = fmaxf((lds[c_l][x4 + 0] - mean) * rstd * ga + be + r.x, 0.f);
        o.y = fmaxf((lds[c_l][x4 + 1] - mean) * rstd * ga + be + r.y, 0.f);
        o.z = fmaxf((lds[c_l][x4 + 2] - mean) * rstd * ga + be + r.z, 0.f);
        o.w = fmaxf((lds[c_l][x4 + 3] - mean) * rstd * ga + be + r.w, 0.f);
        st4(&out[((b << 8) + c) * 4096 + (y << 6) + x4], o);
    }
}

extern "C" void kernel_launch(void* const* d_in, const int* in_sizes, int n_in,
                              void* d_out, int out_size, void* d_ws, size_t ws_size,
                              hipStream_t stream) {
    (void)in_sizes; (void)n_in; (void)out_size; (void)ws_size;
    const float* x      = (const float*)d_in[0];
    const float* w_off1 = (const float*)d_in[1];
    const float* b_off1 = (const float*)d_in[2];
    const float* w_off2 = (const float*)d_in[3];
    const float* b_off2 = (const float*)d_in[4];
    const float* w_def1 = (const float*)d_in[5];
    const float* w_def2 = (const float*)d_in[6];
    const float* gamma1 = (const float*)d_in[7];
    const float* beta1  = (const float*)d_in[8];
    const float* gamma2 = (const float*)d_in[9];
    const float* beta2  = (const float*)d_in[10];
    float* out = (float*)d_out;

    float* ws = (float*)d_ws;
    float* xn     = ws;                    // 4,194,304
    float* offb   = xn + 4194304;          // 294,912
    float* wTa    = offb + 294912;         // 589,824
    float* wTb    = wTa + 589824;          // 589,824
    float* wO1    = wTb + 589824;          // 41,472
    float* wO2    = wO1 + 41472;           // 41,472
    float* stats1 = wO2 + 41472;           // 256
    float* stats2 = stats1 + 256;          // 256
    float* t1 = out;                       // reuse d_out as stage-1 NHWC activation

    prep_wdef<<<4608, 256, 0, stream>>>(w_def1, w_def2, wTa, wTb);
    prep_woff<<<324, 256, 0, stream>>>(w_off1, w_off2, wO1, wO2);
    transpose_to_nhwc<<<1024, 256, 0, stream>>>(x, xn);
    offset_conv<<<1152, 256, 0, stream>>>(xn, wO1, b_off1, offb);
    deform_conv_k<<<512, 256, 0, stream>>>(xn, offb, wTa, t1);
    gn_stats<<<128, 256, 0, stream>>>(t1, stats1);
    gn_apply_relu<<<4096, 256, 0, stream>>>(t1, stats1, gamma1, beta1);
    offset_conv<<<1152, 256, 0, stream>>>(t1, wO2, b_off2, offb);
    deform_conv_k<<<512, 256, 0, stream>>>(t1, offb, wTb, xn);   // stage-2 deform out -> xn buffer
    gn_stats<<<128, 256, 0, stream>>>(xn, stats2);
    final_kernel<<<1024, 256, 0, stream>>>(xn, stats2, gamma2, beta2, x, out);
}

// Round 2
// 399.170 us; speedup vs baseline: 4.9679x; 4.9679x over previous
//
#include <hip/hip_runtime.h>

typedef unsigned int uint;
typedef unsigned short ushort;
typedef __attribute__((ext_vector_type(8))) short bfrag_t;
typedef __attribute__((ext_vector_type(4))) short s4_t;
typedef __attribute__((ext_vector_type(4))) float f4_t;

#define EPSV 1e-5f

__device__ __forceinline__ float4 ld4(const float* p) { return *(const float4*)p; }
__device__ __forceinline__ void st4(float* p, float4 v) { *(float4*)p = v; }

__device__ __forceinline__ ushort f2bf(float f) {
    union { float f; uint u; } v; v.f = f;
    uint r = v.u + 0x7fffu + ((v.u >> 16) & 1u);
    return (ushort)(r >> 16);
}
__device__ __forceinline__ float bf2f(ushort s) {
    union { uint u; float f; } v; v.u = ((uint)s) << 16;
    return v.f;
}
__device__ __forceinline__ float bfhi(uint u) { union { uint u; float f; } v; v.u = u & 0xffff0000u; return v.f; }
__device__ __forceinline__ float bflo(uint u) { union { uint u; float f; } v; v.u = u << 16; return v.f; }

// wT[(k*256+co)*256+ci] = bf16(w[co][ci][k])
__global__ __launch_bounds__(256) void prep_wdef_bf16(const float* __restrict__ w1, const float* __restrict__ w2,
                                                      ushort* __restrict__ o1, ushort* __restrict__ o2) {
    int idx = blockIdx.x * 256 + threadIdx.x;           // 2*589824
    int sel = idx >= 589824;
    int i = sel ? idx - 589824 : idx;
    const float* w = sel ? w2 : w1;
    ushort* o = sel ? o2 : o1;
    int ci = i & 255, co = (i >> 8) & 255, k = i >> 16;
    o[i] = f2bf(w[(((co << 8) + ci) * 9) + k]);
}

// wO[(k*32+co)*256+ci] = co<18 ? bf16(w[co][ci][k]) : 0
__global__ __launch_bounds__(256) void prep_woff_bf16(const float* __restrict__ w1, const float* __restrict__ w2,
                                                      ushort* __restrict__ o1, ushort* __restrict__ o2) {
    int idx = blockIdx.x * 256 + threadIdx.x;           // 2*73728
    int sel = idx >= 73728;
    int i = sel ? idx - 73728 : idx;
    const float* w = sel ? w2 : w1;
    ushort* o = sel ? o2 : o1;
    int ci = i & 255, co = (i >> 8) & 31, k = i >> 13;
    o[i] = (co < 18) ? f2bf(w[(((co << 8) + ci) * 9) + k]) : (ushort)0;
}

// NCHW fp32 -> NHWC bf16
__global__ __launch_bounds__(256) void transpose_to_nhwc_bf16(const float* __restrict__ in, ushort* __restrict__ out) {
    __shared__ float lds[64][65];
    int bid = blockIdx.x;                 // b*256 + y*4 + cb
    int cb = bid & 3, y = (bid >> 2) & 63, b = bid >> 8;
    int c0 = cb << 6;
    int tid = threadIdx.x;
#pragma unroll
    for (int i = 0; i < 4; ++i) {
        int q = tid + (i << 8);
        int c_l = q >> 4, x4 = (q & 15) << 2;
        float4 v = ld4(&in[((b * 256 + c0 + c_l) << 12) + (y << 6) + x4]);
        lds[c_l][x4 + 0] = v.x; lds[c_l][x4 + 1] = v.y; lds[c_l][x4 + 2] = v.z; lds[c_l][x4 + 3] = v.w;
    }
    __syncthreads();
#pragma unroll
    for (int i = 0; i < 4; ++i) {
        int q = tid + (i << 8);
        int x_l = q >> 4, c4 = (q & 15) << 2;
        s4_t v;
        v.x = (short)f2bf(lds[c4 + 0][x_l]); v.y = (short)f2bf(lds[c4 + 1][x_l]);
        v.z = (short)f2bf(lds[c4 + 2][x_l]); v.w = (short)f2bf(lds[c4 + 3][x_l]);
        *(s4_t*)&out[(((b << 12) + (y << 6) + x_l) << 8) + c0 + c4] = v;
    }
}

// Unified MFMA conv kernel.
// xb: NHWC bf16 input. offb: [px][18] offsets (DEFORM only). wT: [k][NCO][256] bf16.
// NCO=256: deform, 4 waves split co (64 each), each wave 4 m-tiles x 4 n-tiles.
// NCO=32 : offset conv, wave w owns m-tile w, 2 n-tiles, bias added, out [px][18] fp32.
template<int NCO, bool DEFORM, bool OUTBF>
__global__ __launch_bounds__(256) void dconv(
    const ushort* __restrict__ xb, const float* __restrict__ offb,
    const ushort* __restrict__ wT, const float* __restrict__ bias,
    float* __restrict__ outF, ushort* __restrict__ outB)
{
    __shared__ short As[64][260];         // A-tile: 64 px x 256 k (pitch 260)
    __shared__ int   cidx[4][64];
    __shared__ float cwt[4][64];

    const int tid = threadIdx.x;
    const int wave = tid >> 6, lane = tid & 63;
    const int lq = lane >> 4, lr = lane & 15;
    const int px0 = blockIdx.x << 6;

    constexpr int MT = (NCO == 256) ? 4 : 1;
    constexpr int NT = (NCO == 256) ? 4 : 2;

    f4_t acc[MT][NT];
#pragma unroll
    for (int mt = 0; mt < MT; ++mt)
#pragma unroll
        for (int nt = 0; nt < NT; ++nt) acc[mt][nt] = (f4_t){0.f, 0.f, 0.f, 0.f};

    const int gpx = tid >> 2;           // gather: pixel
    const int gci = (tid & 3) << 6;     // gather: ci start (64 wide)
    uint* Au = (uint*)&As[0][0];
    const int grow = gpx * 130 + (gci >> 1);

    for (int k = 0; k < 9; ++k) {
        const int ky = k / 3, kx = k - ky * 3;
        if constexpr (DEFORM) {
            if (tid < 64) {
                int px = px0 + tid;
                int b = px >> 12, y = (px >> 6) & 63, x = px & 63;
                float dy = offb[px * 18 + 2 * k];
                float dx = offb[px * 18 + 2 * k + 1];
                float py = dy + (float)(y - 1 + ky);
                float pxx = dx + (float)(x - 1 + kx);
                float y0f = floorf(py), x0f = floorf(pxx);
                float ly = py - y0f, lx = pxx - x0f;
                int y0 = (int)y0f, x0 = (int)x0f;
                int y1 = y0 + 1, x1 = x0 + 1;
                int base = b << 12;
                bool vy0 = (y0 >= 0) && (y0 < 64), vy1 = (y1 >= 0) && (y1 < 64);
                bool vx0 = (x0 >= 0) && (x0 < 64), vx1 = (x1 >= 0) && (x1 < 64);
                cidx[0][tid] = (vy0 && vx0) ? ((base + (y0 << 6) + x0) << 8) : -1;
                cidx[1][tid] = (vy0 && vx1) ? ((base + (y0 << 6) + x1) << 8) : -1;
                cidx[2][tid] = (vy1 && vx0) ? ((base + (y1 << 6) + x0) << 8) : -1;
                cidx[3][tid] = (vy1 && vx1) ? ((base + (y1 << 6) + x1) << 8) : -1;
                cwt[0][tid] = (1.f - ly) * (1.f - lx);
                cwt[1][tid] = (1.f - ly) * lx;
                cwt[2][tid] = ly * (1.f - lx);
                cwt[3][tid] = ly * lx;
            }
        }
        __syncthreads();   // corners visible; previous GEMM done with As
        if constexpr (DEFORM) {
            int i0 = cidx[0][gpx], i1 = cidx[1][gpx], i2 = cidx[2][gpx], i3 = cidx[3][gpx];
            float w0 = cwt[0][gpx], w1 = cwt[1][gpx], w2 = cwt[2][gpx], w3 = cwt[3][gpx];
#pragma unroll
            for (int u = 0; u < 8; ++u) {
                int cio = gci + (u << 3);
                float f0 = 0.f, f1 = 0.f, f2 = 0.f, f3 = 0.f, f4 = 0.f, f5 = 0.f, f6 = 0.f, f7 = 0.f;
#define CORNER(ii, ww) if (ii >= 0) { \
                    uint4 q = *(const uint4*)(xb + ii + cio); \
                    f0 += ww * bflo(q.x); f1 += ww * bfhi(q.x); \
                    f2 += ww * bflo(q.y); f3 += ww * bfhi(q.y); \
                    f4 += ww * bflo(q.z); f5 += ww * bfhi(q.z); \
                    f6 += ww * bflo(q.w); f7 += ww * bfhi(q.w); }
                CORNER(i0, w0) CORNER(i1, w1) CORNER(i2, w2) CORNER(i3, w3)
#undef CORNER
                Au[grow + (u << 2) + 0] = (uint)f2bf(f0) | ((uint)f2bf(f1) << 16);
                Au[grow + (u << 2) + 1] = (uint)f2bf(f2) | ((uint)f2bf(f3) << 16);
                Au[grow + (u << 2) + 2] = (uint)f2bf(f4) | ((uint)f2bf(f5) << 16);
                Au[grow + (u << 2) + 3] = (uint)f2bf(f6) | ((uint)f2bf(f7) << 16);
            }
        } else {
            int px = px0 + gpx;
            int b = px >> 12, y = (px >> 6) & 63, x = px & 63;
            int yy = y + ky - 1, xx = x + kx - 1;
            bool valid = (yy >= 0) && (yy < 64) && (xx >= 0) && (xx < 64);
            const ushort* src = xb + (((((b << 6) + yy) << 6) + xx) << 8) + gci;
#pragma unroll
            for (int u = 0; u < 8; ++u) {
                uint4 q = make_uint4(0u, 0u, 0u, 0u);
                if (valid) q = *(const uint4*)(src + (u << 3));
                Au[grow + (u << 2) + 0] = q.x;
                Au[grow + (u << 2) + 1] = q.y;
                Au[grow + (u << 2) + 2] = q.z;
                Au[grow + (u << 2) + 3] = q.w;
            }
        }
        __syncthreads();
        const int nbase = (NCO == 256) ? (wave << 6) : 0;
        const ushort* wk = wT + (((k * NCO + nbase)) << 8);
#pragma unroll
        for (int s = 0; s < 8; ++s) {
            const int kb = (s << 5) + (lq << 3);
            bfrag_t bfr[NT];
#pragma unroll
            for (int nt = 0; nt < NT; ++nt)
                bfr[nt] = *(const bfrag_t*)(wk + (((nt << 4) + lr) << 8) + kb);
            bfrag_t afr[MT];
#pragma unroll
            for (int mt = 0; mt < MT; ++mt) {
                int pxl = ((NCO == 256) ? (mt << 4) : (wave << 4)) + lr;
                const short* ap = &As[pxl][kb];
                s4_t lo = *(const s4_t*)ap, hi = *(const s4_t*)(ap + 4);
                afr[mt] = __builtin_shufflevector(lo, hi, 0, 1, 2, 3, 4, 5, 6, 7);
            }
#pragma unroll
            for (int mt = 0; mt < MT; ++mt)
#pragma unroll
                for (int nt = 0; nt < NT; ++nt)
                    acc[mt][nt] = __builtin_amdgcn_mfma_f32_16x16x32_bf16(afr[mt], bfr[nt], acc[mt][nt], 0, 0, 0);
        }
    }
    if constexpr (NCO == 32) {
#pragma unroll
        for (int nt = 0; nt < NT; ++nt) {
            int co = (nt << 4) + lr;
            if (co < 18) {
                float bv = bias[co];
#pragma unroll
                for (int r = 0; r < 4; ++r) {
                    int pxl = (wave << 4) + (lq << 2) + r;
                    outF[(px0 + pxl) * 18 + co] = acc[0][nt][r] + bv;
                }
            }
        }
    } else {
#pragma unroll
        for (int mt = 0; mt < MT; ++mt)
#pragma unroll
            for (int nt = 0; nt < NT; ++nt) {
                int co = (wave << 6) + (nt << 4) + lr;
#pragma unroll
                for (int r = 0; r < 4; ++r) {
                    int pxl = (mt << 4) + (lq << 2) + r;
                    int o = (((px0 + pxl)) << 8) + co;
                    if constexpr (OUTBF) outB[o] = f2bf(acc[mt][nt][r]);
                    else outF[o] = acc[mt][nt][r];
                }
            }
    }
}

// GroupNorm stats over NHWC buffer (fp32 or bf16): per (b,g) mean & rstd
template<bool BF>
__global__ __launch_bounds__(256) void gn_statsT(const void* __restrict__ bufv, float* __restrict__ stats) {
    int bid = blockIdx.x;     // b*32+g
    int b = bid >> 5, g = bid & 31;
    float s = 0.f, s2 = 0.f;
    if constexpr (BF) {
        const ushort* p = (const ushort*)bufv + (b << 20) + (g << 3);
        for (int px = threadIdx.x; px < 4096; px += 256) {
            uint4 q = *(const uint4*)(p + (px << 8));
            float v0 = bflo(q.x), v1 = bfhi(q.x), v2 = bflo(q.y), v3 = bfhi(q.y);
            float v4 = bflo(q.z), v5 = bfhi(q.z), v6 = bflo(q.w), v7 = bfhi(q.w);
            s += v0 + v1 + v2 + v3 + v4 + v5 + v6 + v7;
            s2 += v0 * v0 + v1 * v1 + v2 * v2 + v3 * v3 + v4 * v4 + v5 * v5 + v6 * v6 + v7 * v7;
        }
    } else {
        const float* p = (const float*)bufv + (b << 20) + (g << 3);
        for (int px = threadIdx.x; px < 4096; px += 256) {
            float4 a = ld4(p + (px << 8));
            float4 c = ld4(p + (px << 8) + 4);
            s += a.x + a.y + a.z + a.w + c.x + c.y + c.z + c.w;
            s2 += a.x * a.x + a.y * a.y + a.z * a.z + a.w * a.w + c.x * c.x + c.y * c.y + c.z * c.z + c.w * c.w;
        }
    }
#pragma unroll
    for (int o = 32; o > 0; o >>= 1) { s += __shfl_down(s, o, 64); s2 += __shfl_down(s2, o, 64); }
    __shared__ float ws1[4], ws2[4];
    int wv = threadIdx.x >> 6, lane = threadIdx.x & 63;
    if (lane == 0) { ws1[wv] = s; ws2[wv] = s2; }
    __syncthreads();
    if (threadIdx.x == 0) {
        float t1 = ws1[0] + ws1[1] + ws1[2] + ws1[3];
        float t2 = ws2[0] + ws2[1] + ws2[2] + ws2[3];
        float mean = t1 * (1.f / 32768.f);
        float var = t2 * (1.f / 32768.f) - mean * mean;
        stats[bid * 2] = mean;
        stats[bid * 2 + 1] = rsqrtf(var + EPSV);
    }
}

// GN + ReLU on fp32 NHWC -> bf16 NHWC
__global__ __launch_bounds__(256) void gn_apply_relu_bf16(const float* __restrict__ buf, const float* __restrict__ stats,
                                                          const float* __restrict__ gamma, const float* __restrict__ beta,
                                                          ushort* __restrict__ outb) {
    int q = blockIdx.x * 256 + threadIdx.x;   // 1,048,576
    int e0 = q << 2;
    int c0 = e0 & 255;
    int b = e0 >> 20;
    int g = c0 >> 3;
    float mean = stats[((b << 5) + g) * 2];
    float rstd = stats[((b << 5) + g) * 2 + 1];
    float4 v = ld4(&buf[e0]);
    float4 ga = ld4(&gamma[c0]);
    float4 be = ld4(&beta[c0]);
    s4_t o;
    o.x = (short)f2bf(fmaxf((v.x - mean) * rstd * ga.x + be.x, 0.f));
    o.y = (short)f2bf(fmaxf((v.y - mean) * rstd * ga.y + be.y, 0.f));
    o.z = (short)f2bf(fmaxf((v.z - mean) * rstd * ga.z + be.z, 0.f));
    o.w = (short)f2bf(fmaxf((v.w - mean) * rstd * ga.w + be.w, 0.f));
    *(s4_t*)&outb[e0] = o;
}

// NHWC bf16 -> NCHW with fused GN2 + residual + ReLU
__global__ __launch_bounds__(256) void final_bf16(const ushort* __restrict__ v2, const float* __restrict__ stats,
                                                  const float* __restrict__ gamma, const float* __restrict__ beta,
                                                  const float* __restrict__ xin, float* __restrict__ out) {
    __shared__ float lds[64][65];
    int bid = blockIdx.x;
    int cb = bid & 3, y = (bid >> 2) & 63, b = bid >> 8;
    int c0 = cb << 6;
    int tid = threadIdx.x;
#pragma unroll
    for (int i = 0; i < 4; ++i) {
        int q = tid + (i << 8);
        int x_l = q >> 4, c4 = (q & 15) << 2;
        s4_t v = *(const s4_t*)&v2[(((b << 12) + (y << 6) + x_l) << 8) + c0 + c4];
        lds[c4 + 0][x_l] = bf2f((ushort)v.x); lds[c4 + 1][x_l] = bf2f((ushort)v.y);
        lds[c4 + 2][x_l] = bf2f((ushort)v.z); lds[c4 + 3][x_l] = bf2f((ushort)v.w);
    }
    __syncthreads();
#pragma unroll
    for (int i = 0; i < 4; ++i) {
        int q = tid + (i << 8);
        int c_l = q >> 4, x4 = (q & 15) << 2;
        int c = c0 + c_l;
        int g = c >> 3;
        float mean = stats[((b << 5) + g) * 2];
        float rstd = stats[((b << 5) + g) * 2 + 1];
        float ga = gamma[c], be = beta[c];
        const float* xp = &xin[((b << 8) + c) * 4096 + (y << 6) + x4];
        float4 r = ld4(xp);
        float4 o;
        o.x = fmaxf((lds[c_l][x4 + 0] - mean) * rstd * ga + be + r.x, 0.f);
        o.y = fmaxf((lds[c_l][x4 + 1] - mean) * rstd * ga + be + r.y, 0.f);
        o.z = fmaxf((lds[c_l][x4 + 2] - mean) * rstd * ga + be + r.z, 0.f);
        o.w = fmaxf((lds[c_l][x4 + 3] - mean) * rstd * ga + be + r.w, 0.f);
        st4(&out[((b << 8) + c) * 4096 + (y << 6) + x4], o);
    }
}

extern "C" void kernel_launch(void* const* d_in, const int* in_sizes, int n_in,
                              void* d_out, int out_size, void* d_ws, size_t ws_size,
                              hipStream_t stream) {
    (void)in_sizes; (void)n_in; (void)out_size; (void)ws_size;
    const float* x      = (const float*)d_in[0];
    const float* w_off1 = (const float*)d_in[1];
    const float* b_off1 = (const float*)d_in[2];
    const float* w_off2 = (const float*)d_in[3];
    const float* b_off2 = (const float*)d_in[4];
    const float* w_def1 = (const float*)d_in[5];
    const float* w_def2 = (const float*)d_in[6];
    const float* gamma1 = (const float*)d_in[7];
    const float* beta1  = (const float*)d_in[8];
    const float* gamma2 = (const float*)d_in[9];
    const float* beta2  = (const float*)d_in[10];
    float* out = (float*)d_out;

    float* ws = (float*)d_ws;
    float*  xb_f   = ws;                      // 2,097,152 floats: xb bf16 (stage1) / v2 bf16 (stage2)
    float*  xb2_f  = xb_f + 2097152;          // 2,097,152: xb2 bf16
    float*  wT1_f  = xb2_f + 2097152;         // 294,912
    float*  wT2_f  = wT1_f + 294912;          // 294,912
    float*  wO1_f  = wT2_f + 294912;          // 36,864
    float*  wO2_f  = wO1_f + 36864;           // 36,864
    float*  offb   = wO2_f + 36864;           // 294,912 (16384 x 18)
    float*  stats1 = offb + 294912;           // 256
    float*  stats2 = stats1 + 256;            // 256

    ushort* xb  = (ushort*)xb_f;
    ushort* v2b = (ushort*)xb_f;              // reuses xb slot after stage 1
    ushort* xb2 = (ushort*)xb2_f;
    ushort* wT1 = (ushort*)wT1_f;
    ushort* wT2 = (ushort*)wT2_f;
    ushort* wO1 = (ushort*)wO1_f;
    ushort* wO2 = (ushort*)wO2_f;
    float* t1 = out;                          // stage-1 deform output (fp32 NHWC) in d_out

    prep_wdef_bf16<<<4608, 256, 0, stream>>>(w_def1, w_def2, wT1, wT2);
    prep_woff_bf16<<<576, 256, 0, stream>>>(w_off1, w_off2, wO1, wO2);
    transpose_to_nhwc_bf16<<<1024, 256, 0, stream>>>(x, xb);

    dconv<32, false, false><<<256, 256, 0, stream>>>(xb, nullptr, wO1, b_off1, offb, nullptr);
    dconv<256, true, false><<<256, 256, 0, stream>>>(xb, offb, wT1, nullptr, t1, nullptr);
    gn_statsT<false><<<128, 256, 0, stream>>>(t1, stats1);
    gn_apply_relu_bf16<<<4096, 256, 0, stream>>>(t1, stats1, gamma1, beta1, xb2);

    dconv<32, false, false><<<256, 256, 0, stream>>>(xb2, nullptr, wO2, b_off2, offb, nullptr);
    dconv<256, true, true><<<256, 256, 0, stream>>>(xb2, offb, wT2, nullptr, nullptr, v2b);
    gn_statsT<true><<<128, 256, 0, stream>>>(v2b, stats2);
    final_bf16<<<1024, 256, 0, stream>>>(v2b, stats2, gamma2, beta2, x, out);
}